// Round 2
// baseline (11219.115 us; speedup 1.0000x reference)
//
#include <hip/hip_runtime.h>
#include <math.h>

#define DEV __device__ __forceinline__

DEV float sigmoid_(float x) { return 1.0f / (1.0f + __expf(-x)); }
DEV float tanh_(float x) {
    float e = __expf(2.0f * x);
    return 1.0f - 2.0f / (e + 1.0f);
}

// Fused ConvLSTM timestep: z = conv3x3(concat(x_t, h_{t-1})) + b; gates; state update.
// xin:  [B,T,Cin,H,W] layer input
// w:    [4*hid, Cin+hid, 3, 3]
// bias: [4*hid]
// hbuf: [B,T,hid,H,W]  (h_{t-1} read from t-1 slice; h_t written to t slice)
// cbuf: [B,hid,H,W]    (updated in place)
__global__ void convlstm_step(const float* __restrict__ xin,
                              const float* __restrict__ w,
                              const float* __restrict__ bias,
                              float* __restrict__ hbuf,
                              float* __restrict__ cbuf,
                              int t, int B, int T, int Cin, int hid, int H, int W)
{
    const int HW = H * W;
    int idx = blockIdx.x * blockDim.x + threadIdx.x;
    int total = B * hid * HW;
    if (idx >= total) return;

    int xw = idx % W;
    int y  = (idx / W) % H;
    int oc = (idx / HW) % hid;
    int b  = idx / (hid * HW);

    float acc0 = bias[0 * hid + oc];   // i
    float acc1 = bias[1 * hid + oc];   // f
    float acc2 = bias[2 * hid + oc];   // o
    float acc3 = bias[3 * hid + oc];   // g

    const int Ctot = Cin + hid;
    const float* xslice = xin  + (size_t)(b * T + t) * Cin * HW;
    const float* hslice = hbuf + (size_t)(b * T + (t - 1)) * hid * HW;

    for (int ic = 0; ic < Ctot; ++ic) {
        const float* src;
        if (ic < Cin) {
            src = xslice + (size_t)ic * HW;
        } else {
            if (t == 0) continue;      // h_prev == 0
            src = hslice + (size_t)(ic - Cin) * HW;
        }
        // 3x3 neighborhood with zero padding
        float v[3][3];
        #pragma unroll
        for (int dy = 0; dy < 3; ++dy) {
            int yy = y + dy - 1;
            #pragma unroll
            for (int dx = 0; dx < 3; ++dx) {
                int xx = xw + dx - 1;
                bool ok = (yy >= 0) && (yy < H) && (xx < W) && (xx >= 0) && (yy < H);
                v[dy][dx] = ((yy >= 0) && (yy < H) && (xx >= 0) && (xx < W)) ? src[yy * W + xx] : 0.0f;
                (void)ok;
            }
        }
        const float* w0 = w + ((size_t)(0 * hid + oc) * Ctot + ic) * 9;
        const float* w1 = w + ((size_t)(1 * hid + oc) * Ctot + ic) * 9;
        const float* w2 = w + ((size_t)(2 * hid + oc) * Ctot + ic) * 9;
        const float* w3 = w + ((size_t)(3 * hid + oc) * Ctot + ic) * 9;
        #pragma unroll
        for (int k = 0; k < 9; ++k) {
            float vv = v[k / 3][k % 3];
            acc0 = fmaf(vv, w0[k], acc0);
            acc1 = fmaf(vv, w1[k], acc1);
            acc2 = fmaf(vv, w2[k], acc2);
            acc3 = fmaf(vv, w3[k], acc3);
        }
    }

    float ig = sigmoid_(acc0);
    float fg = sigmoid_(acc1);
    float og = sigmoid_(acc2);
    float gg = tanh_(acc3);

    float cprev = (t == 0) ? 0.0f : cbuf[idx];
    float cn = fg * cprev + ig * gg;
    cbuf[idx] = cn;
    float hn = og * tanh_(cn);
    hbuf[((size_t)(b * T + t) * hid + oc) * HW + y * W + xw] = hn;
}

// Per-channel sum/sumsq over [B*T, H*W] for BatchNorm (training stats).
// stats: [C][2] floats, must be zeroed beforehand.
__global__ void bn_stats(const float* __restrict__ hbuf, float* __restrict__ stats,
                         int BT, int C, int HW)
{
    int c = blockIdx.x;
    float s = 0.0f, s2 = 0.0f;
    for (int bt = blockIdx.y; bt < BT; bt += gridDim.y) {
        const float* p = hbuf + ((size_t)bt * C + c) * HW;
        for (int i = threadIdx.x; i < HW; i += blockDim.x) {
            float v = p[i];
            s += v;
            s2 += v * v;
        }
    }
    __shared__ float ssum[256];
    __shared__ float ssq[256];
    int tid = threadIdx.x;
    ssum[tid] = s; ssq[tid] = s2;
    __syncthreads();
    for (int off = 128; off > 0; off >>= 1) {
        if (tid < off) { ssum[tid] += ssum[tid + off]; ssq[tid] += ssq[tid + off]; }
        __syncthreads();
    }
    if (tid == 0) {
        atomicAdd(&stats[2 * c + 0], ssum[0]);
        atomicAdd(&stats[2 * c + 1], ssq[0]);
    }
}

// BN (training stats) + ReLU + MaxPool(2,2). out: [B,T,C,H/2,W/2]
__global__ void bn_relu_pool(const float* __restrict__ hbuf,
                             const float* __restrict__ stats,
                             const float* __restrict__ gamma,
                             const float* __restrict__ beta,
                             float* __restrict__ out,
                             int BT, int C, int H, int W, float invN)
{
    int Ho = H / 2, Wo = W / 2;
    int idx = blockIdx.x * blockDim.x + threadIdx.x;
    int total = BT * C * Ho * Wo;
    if (idx >= total) return;
    int xo = idx % Wo;
    int yo = (idx / Wo) % Ho;
    int c  = (idx / (Wo * Ho)) % C;
    int bt = idx / (C * Ho * Wo);

    float mean = stats[2 * c + 0] * invN;
    float var  = stats[2 * c + 1] * invN - mean * mean;
    float sc = gamma[c] * rsqrtf(var + 1e-5f);
    float sh = beta[c] - mean * sc;

    const float* p = hbuf + ((size_t)bt * C + c) * (H * W) + (2 * yo) * W + 2 * xo;
    float a0 = fmaxf(fmaf(p[0],     sc, sh), 0.0f);
    float a1 = fmaxf(fmaf(p[1],     sc, sh), 0.0f);
    float a2 = fmaxf(fmaf(p[W],     sc, sh), 0.0f);
    float a3 = fmaxf(fmaf(p[W + 1], sc, sh), 0.0f);
    out[idx] = fmaxf(fmaxf(a0, a1), fmaxf(a2, a3));
}

// FC head: feat [BT,1024] -> relu(fc1) [BT,128] -> fc2 [BT,2]
__global__ __launch_bounds__(128) void fc_head(const float* __restrict__ feat,
                                               const float* __restrict__ fc1w,
                                               const float* __restrict__ fc1b,
                                               const float* __restrict__ fc2w,
                                               const float* __restrict__ fc2b,
                                               float* __restrict__ out)
{
    __shared__ float sf[1024];
    __shared__ float y1[128];
    int bt = blockIdx.x;
    const float* f = feat + (size_t)bt * 1024;
    for (int i = threadIdx.x; i < 1024; i += 128) sf[i] = f[i];
    __syncthreads();
    int k = threadIdx.x;
    float acc = fc1b[k];
    const float* wk = fc1w + (size_t)k * 1024;
    for (int d = 0; d < 1024; ++d) acc = fmaf(sf[d], wk[d], acc);
    y1[k] = fmaxf(acc, 0.0f);
    __syncthreads();
    if (k < 2) {
        float a = fc2b[k];
        const float* w2 = fc2w + k * 128;
        for (int j = 0; j < 128; ++j) a = fmaf(y1[j], w2[j], a);
        out[(size_t)bt * 2 + k] = a;
    }
}

extern "C" void kernel_launch(void* const* d_in, const int* in_sizes, int n_in,
                              void* d_out, int out_size, void* d_ws, size_t ws_size,
                              hipStream_t stream)
{
    const int B = 8, T = 40;
    const float* x = (const float*)d_in[0];

    struct LayerCfg { int Cin, hid, H, W; };
    const LayerCfg L[4] = { {1, 16, 64, 64}, {16, 32, 32, 32}, {32, 64, 16, 16}, {64, 64, 8, 8} };

    // workspace layout (floats)
    float* hbuf  = (float*)d_ws;                       // max 8*40*16*64*64 = 20,971,520 f
    float* pbuf  = hbuf + (size_t)20971520;            // max 8*40*16*32*32 =  5,242,880 f
    float* cbuf  = pbuf + (size_t)5242880;             // max 8*16*64*64    =    524,288 f
    float* stats = cbuf + (size_t)524288;              // 2*64 f

    const float* in = x;
    for (int l = 0; l < 4; ++l) {
        const float* w     = (const float*)d_in[1 + 4 * l];
        const float* bias  = (const float*)d_in[2 + 4 * l];
        const float* gamma = (const float*)d_in[3 + 4 * l];
        const float* beta  = (const float*)d_in[4 + 4 * l];
        const int Cin = L[l].Cin, hid = L[l].hid, H = L[l].H, W = L[l].W;
        const int HW = H * W;

        int total = B * hid * HW;
        int blocks = (total + 255) / 256;
        for (int t = 0; t < T; ++t) {
            convlstm_step<<<blocks, 256, 0, stream>>>(in, w, bias, hbuf, cbuf,
                                                      t, B, T, Cin, hid, H, W);
        }

        hipMemsetAsync(stats, 0, 2 * hid * sizeof(float), stream);
        bn_stats<<<dim3(hid, 80), 256, 0, stream>>>(hbuf, stats, B * T, hid, HW);

        int ptotal = B * T * hid * (H / 2) * (W / 2);
        int pblocks = (ptotal + 255) / 256;
        float invN = 1.0f / ((float)(B * T) * (float)HW);
        bn_relu_pool<<<pblocks, 256, 0, stream>>>(hbuf, stats, gamma, beta, pbuf,
                                                  B * T, hid, H, W, invN);
        in = pbuf;
    }

    const float* fc1w = (const float*)d_in[17];
    const float* fc1b = (const float*)d_in[18];
    const float* fc2w = (const float*)d_in[19];
    const float* fc2b = (const float*)d_in[20];
    fc_head<<<B * T, 128, 0, stream>>>(pbuf, fc1w, fc1b, fc2w, fc2b, (float*)d_out);
}

// Round 3
// 6988.445 us; speedup vs baseline: 1.6054x; 1.6054x over previous
//
#include <hip/hip_runtime.h>
#include <math.h>

#define DEV __device__ __forceinline__

DEV float sigmoid_(float x) { return 1.0f / (1.0f + __expf(-x)); }
DEV float tanh_(float x) {
    float e = __expf(2.0f * x);
    return 1.0f - 2.0f / (e + 1.0f);
}

// ---------------------------------------------------------------------------
// zx_conv: precompute z_x[b][tc][g][oc][H][W] = bias[g,oc] + conv3x3(x_t, w_x)
// for a chunk of timesteps [t0, t0+TcAct). Fully parallel over B*Tc*hid*HW.
// Each thread computes all 4 gates for one (b,tc,oc,pixel): 9 loads -> 36 FMA.
// ---------------------------------------------------------------------------
__global__ __launch_bounds__(256) void zx_conv(
    const float* __restrict__ xin,   // [B,T,Cin,H,W]
    const float* __restrict__ w,     // [4*hid, Ctot, 3, 3]
    const float* __restrict__ bias,  // [4*hid]
    float* __restrict__ zx,          // [B,TcMax,4,hid,H,W]
    int t0, int TcAct, int TcMax, int B, int T, int Cin, int Ctot,
    int hid, int H, int W)
{
    const int HW = H * W;
    int idx = blockIdx.x * 256 + threadIdx.x;
    int total = B * TcAct * hid * HW;
    if (idx >= total) return;

    int col = idx % W;
    int y   = (idx / W) % H;
    int oc  = (idx / HW) % hid;
    int tc  = (idx / (HW * hid)) % TcAct;
    int b   = idx / (HW * hid * TcAct);

    float a0 = bias[0 * hid + oc];
    float a1 = bias[1 * hid + oc];
    float a2 = bias[2 * hid + oc];
    float a3 = bias[3 * hid + oc];

    const float* xsl = xin + ((size_t)(b * T + t0 + tc) * Cin) * HW;
    for (int ic = 0; ic < Cin; ++ic) {
        const float* src = xsl + (size_t)ic * HW;
        float v[3][3];
        #pragma unroll
        for (int dy = 0; dy < 3; ++dy) {
            int yy = y + dy - 1;
            #pragma unroll
            for (int dx = 0; dx < 3; ++dx) {
                int xx = col + dx - 1;
                v[dy][dx] = (yy >= 0 && yy < H && xx >= 0 && xx < W) ? src[yy * W + xx] : 0.0f;
            }
        }
        const float* w0 = w + ((size_t)(0 * hid + oc) * Ctot + ic) * 9;
        const float* w1 = w + ((size_t)(1 * hid + oc) * Ctot + ic) * 9;
        const float* w2 = w + ((size_t)(2 * hid + oc) * Ctot + ic) * 9;
        const float* w3 = w + ((size_t)(3 * hid + oc) * Ctot + ic) * 9;
        #pragma unroll
        for (int k = 0; k < 9; ++k) {
            float vv = v[k / 3][k % 3];
            a0 = fmaf(vv, w0[k], a0);
            a1 = fmaf(vv, w1[k], a1);
            a2 = fmaf(vv, w2[k], a2);
            a3 = fmaf(vv, w3[k], a3);
        }
    }
    size_t base = ((size_t)(b * TcMax + tc) * 4 * hid) * HW + (size_t)y * W + col;
    zx[base + (size_t)(0 * hid + oc) * HW] = a0;
    zx[base + (size_t)(1 * hid + oc) * HW] = a1;
    zx[base + (size_t)(2 * hid + oc) * HW] = a2;
    zx[base + (size_t)(3 * hid + oc) * HW] = a3;
}

// ---------------------------------------------------------------------------
// step_h: one ConvLSTM timestep, h-recurrence part + gates + state update.
// z = (zx precomputed ? zx : bias [+ conv(x) with global weights]) + conv3x3(h_{t-1})
// Block = (b, oc-group of OCB channels, spatial chunk). h-weights staged in LDS
// ([OCB][hid][36] floats, 144 B per ic -> ds_read_b128 broadcast).
// Each thread computes RPT vertically-adjacent pixels: (RPT+2)*3 neighborhood
// loads feed RPT*36 FMAs per input channel.
// ---------------------------------------------------------------------------
template<int OCB, int RPT, bool USE_ZX>
__global__ __launch_bounds__(256) void step_h(
    const float* __restrict__ xin,   // [B,T,Cin,H,W]  (fallback only)
    const float* __restrict__ zx,    // [B,TcMax,4,hid,H,W] (zx mode)
    const float* __restrict__ w,     // [4*hid, Ctot, 3, 3]
    const float* __restrict__ bias,  // [4*hid]
    float* __restrict__ hbuf,        // [B,T,hid,H,W]
    float* __restrict__ cbuf,        // [B,hid,H,W]
    int t, int tc, int TcMax, int B, int T, int Cin, int hid, int H, int W,
    int nOcg, int BPP)
{
    extern __shared__ float wlds[];  // [OCB][hid][36]
    const int HW = H * W;
    const int Ctot = Cin + hid;

    int blk   = blockIdx.x;
    int chunk = blk % BPP;
    int ocg   = (blk / BPP) % nOcg;
    int b     = blk / (BPP * nOcg);

    // stage h-weights for this block's output channels into LDS
    {
        int tot = OCB * hid * 36;
        for (int i = threadIdx.x; i < tot; i += 256) {
            int ocb = i / (hid * 36);
            int rem = i % (hid * 36);
            int ic  = rem / 36;
            int gk  = rem % 36;
            int g = gk / 9, k = gk % 9;
            int oc = ocg * OCB + ocb;
            wlds[i] = w[((size_t)(g * hid + oc) * Ctot + Cin + ic) * 9 + k];
        }
    }
    __syncthreads();

    const int TPO = 256 / OCB;          // threads per output channel
    int ocb  = threadIdx.x / TPO;
    int p    = threadIdx.x % TPO;
    int oc   = ocg * OCB + ocb;
    int col  = p % W;
    int rowg = p / W;
    const int chunkRows = (TPO / W) * RPT;
    int y0 = chunk * chunkRows + rowg * RPT;

    float z[RPT][4];
    #pragma unroll
    for (int r = 0; r < RPT; ++r) {
        if (USE_ZX) {
            size_t zb = ((size_t)(b * TcMax + tc) * 4 * hid) * HW + (size_t)(y0 + r) * W + col;
            #pragma unroll
            for (int g = 0; g < 4; ++g) z[r][g] = zx[zb + (size_t)(g * hid + oc) * HW];
        } else {
            #pragma unroll
            for (int g = 0; g < 4; ++g) z[r][g] = bias[g * hid + oc];
        }
    }

    const float* hsl = hbuf + ((size_t)(b * T + (t - 1)) * hid) * HW;

    // fallback: x-part with global weights
    if (!USE_ZX) {
        const float* xsl = xin + ((size_t)(b * T + t) * Cin) * HW;
        for (int ic = 0; ic < Cin; ++ic) {
            const float* src = xsl + (size_t)ic * HW;
            float v[RPT + 2][3];
            #pragma unroll
            for (int dy = 0; dy < RPT + 2; ++dy) {
                int yy = y0 + dy - 1;
                #pragma unroll
                for (int dx = 0; dx < 3; ++dx) {
                    int xx = col + dx - 1;
                    v[dy][dx] = (yy >= 0 && yy < H && xx >= 0 && xx < W) ? src[yy * W + xx] : 0.0f;
                }
            }
            float wv[36];
            const float* wp = w + ((size_t)(0 * hid + oc) * Ctot + ic) * 9;
            #pragma unroll
            for (int g = 0; g < 4; ++g) {
                const float* wg = w + ((size_t)(g * hid + oc) * Ctot + ic) * 9;
                #pragma unroll
                for (int k = 0; k < 9; ++k) wv[g * 9 + k] = wg[k];
            }
            (void)wp;
            #pragma unroll
            for (int r = 0; r < RPT; ++r)
                #pragma unroll
                for (int g = 0; g < 4; ++g)
                    #pragma unroll
                    for (int k = 0; k < 9; ++k)
                        z[r][g] = fmaf(v[r + k / 3][k % 3], wv[g * 9 + k], z[r][g]);
        }
    }

    // h-part with LDS weights (skip at t==0: h_prev == 0)
    if (t > 0) {
        for (int ic = 0; ic < hid; ++ic) {
            const float* src = hsl + (size_t)ic * HW;
            float v[RPT + 2][3];
            #pragma unroll
            for (int dy = 0; dy < RPT + 2; ++dy) {
                int yy = y0 + dy - 1;
                #pragma unroll
                for (int dx = 0; dx < 3; ++dx) {
                    int xx = col + dx - 1;
                    v[dy][dx] = (yy >= 0 && yy < H && xx >= 0 && xx < W) ? src[yy * W + xx] : 0.0f;
                }
            }
            float wv[36];
            const float* wp = &wlds[(ocb * hid + ic) * 36];
            #pragma unroll
            for (int j = 0; j < 36; ++j) wv[j] = wp[j];
            #pragma unroll
            for (int r = 0; r < RPT; ++r)
                #pragma unroll
                for (int g = 0; g < 4; ++g)
                    #pragma unroll
                    for (int k = 0; k < 9; ++k)
                        z[r][g] = fmaf(v[r + k / 3][k % 3], wv[g * 9 + k], z[r][g]);
        }
    }

    #pragma unroll
    for (int r = 0; r < RPT; ++r) {
        int y = y0 + r;
        size_t ci = ((size_t)b * hid + oc) * HW + (size_t)y * W + col;
        float cprev = (t == 0) ? 0.0f : cbuf[ci];
        float ig = sigmoid_(z[r][0]);
        float fg = sigmoid_(z[r][1]);
        float og = sigmoid_(z[r][2]);
        float gg = tanh_(z[r][3]);
        float cn = fg * cprev + ig * gg;
        cbuf[ci] = cn;
        hbuf[((size_t)(b * T + t) * hid + oc) * HW + (size_t)y * W + col] = og * tanh_(cn);
    }
}

// ---------------------------------------------------------------------------
// BatchNorm stats / BN+ReLU+Pool / FC head (unchanged from round 2)
// ---------------------------------------------------------------------------
__global__ void bn_stats(const float* __restrict__ hbuf, float* __restrict__ stats,
                         int BT, int C, int HW)
{
    int c = blockIdx.x;
    float s = 0.0f, s2 = 0.0f;
    for (int bt = blockIdx.y; bt < BT; bt += gridDim.y) {
        const float* p = hbuf + ((size_t)bt * C + c) * HW;
        for (int i = threadIdx.x; i < HW; i += blockDim.x) {
            float v = p[i];
            s += v;
            s2 += v * v;
        }
    }
    __shared__ float ssum[256];
    __shared__ float ssq[256];
    int tid = threadIdx.x;
    ssum[tid] = s; ssq[tid] = s2;
    __syncthreads();
    for (int off = 128; off > 0; off >>= 1) {
        if (tid < off) { ssum[tid] += ssum[tid + off]; ssq[tid] += ssq[tid + off]; }
        __syncthreads();
    }
    if (tid == 0) {
        atomicAdd(&stats[2 * c + 0], ssum[0]);
        atomicAdd(&stats[2 * c + 1], ssq[0]);
    }
}

__global__ void bn_relu_pool(const float* __restrict__ hbuf,
                             const float* __restrict__ stats,
                             const float* __restrict__ gamma,
                             const float* __restrict__ beta,
                             float* __restrict__ out,
                             int BT, int C, int H, int W, float invN)
{
    int Ho = H / 2, Wo = W / 2;
    int idx = blockIdx.x * blockDim.x + threadIdx.x;
    int total = BT * C * Ho * Wo;
    if (idx >= total) return;
    int xo = idx % Wo;
    int yo = (idx / Wo) % Ho;
    int c  = (idx / (Wo * Ho)) % C;
    int bt = idx / (C * Ho * Wo);

    float mean = stats[2 * c + 0] * invN;
    float var  = stats[2 * c + 1] * invN - mean * mean;
    float sc = gamma[c] * rsqrtf(var + 1e-5f);
    float sh = beta[c] - mean * sc;

    const float* p = hbuf + ((size_t)bt * C + c) * (H * W) + (2 * yo) * W + 2 * xo;
    float a0 = fmaxf(fmaf(p[0],     sc, sh), 0.0f);
    float a1 = fmaxf(fmaf(p[1],     sc, sh), 0.0f);
    float a2 = fmaxf(fmaf(p[W],     sc, sh), 0.0f);
    float a3 = fmaxf(fmaf(p[W + 1], sc, sh), 0.0f);
    out[idx] = fmaxf(fmaxf(a0, a1), fmaxf(a2, a3));
}

__global__ __launch_bounds__(128) void fc_head(const float* __restrict__ feat,
                                               const float* __restrict__ fc1w,
                                               const float* __restrict__ fc1b,
                                               const float* __restrict__ fc2w,
                                               const float* __restrict__ fc2b,
                                               float* __restrict__ out)
{
    __shared__ float sf[1024];
    __shared__ float y1[128];
    int bt = blockIdx.x;
    const float* f = feat + (size_t)bt * 1024;
    for (int i = threadIdx.x; i < 1024; i += 128) sf[i] = f[i];
    __syncthreads();
    int k = threadIdx.x;
    float acc = fc1b[k];
    const float* wk = fc1w + (size_t)k * 1024;
    for (int d = 0; d < 1024; ++d) acc = fmaf(sf[d], wk[d], acc);
    y1[k] = fmaxf(acc, 0.0f);
    __syncthreads();
    if (k < 2) {
        float a = fc2b[k];
        const float* w2 = fc2w + k * 128;
        for (int j = 0; j < 128; ++j) a = fmaf(y1[j], w2[j], a);
        out[(size_t)bt * 2 + k] = a;
    }
}

// ---------------------------------------------------------------------------
// Host
// ---------------------------------------------------------------------------
static void launch_step(int l, bool use_zx,
                        const float* in, const float* zbuf, const float* w,
                        const float* bias, float* hbuf, float* cbuf,
                        int t, int tc, int TcMax, int B, int T,
                        int Cin, int hid, int H, int W, hipStream_t stream)
{
    const int OCB = (l == 3) ? 4 : 1;
    const int RPT = (l < 2) ? 2 : 1;
    const int HW = H * W;
    const int TPO = 256 / OCB;
    const int CH = TPO * RPT;          // pixels per block
    const int BPP = HW / CH;           // blocks per plane (>=1 by construction)
    const int nOcg = hid / OCB;
    const int blocks = B * nOcg * BPP;
    const size_t lds = (size_t)OCB * hid * 36 * sizeof(float);

    if (use_zx) {
        switch (l) {
            case 0: step_h<1, 2, true><<<blocks, 256, lds, stream>>>(in, zbuf, w, bias, hbuf, cbuf, t, tc, TcMax, B, T, Cin, hid, H, W, nOcg, BPP); break;
            case 1: step_h<1, 2, true><<<blocks, 256, lds, stream>>>(in, zbuf, w, bias, hbuf, cbuf, t, tc, TcMax, B, T, Cin, hid, H, W, nOcg, BPP); break;
            case 2: step_h<1, 1, true><<<blocks, 256, lds, stream>>>(in, zbuf, w, bias, hbuf, cbuf, t, tc, TcMax, B, T, Cin, hid, H, W, nOcg, BPP); break;
            case 3: step_h<4, 1, true><<<blocks, 256, lds, stream>>>(in, zbuf, w, bias, hbuf, cbuf, t, tc, TcMax, B, T, Cin, hid, H, W, nOcg, BPP); break;
        }
    } else {
        switch (l) {
            case 0: step_h<1, 2, false><<<blocks, 256, lds, stream>>>(in, zbuf, w, bias, hbuf, cbuf, t, tc, TcMax, B, T, Cin, hid, H, W, nOcg, BPP); break;
            case 1: step_h<1, 2, false><<<blocks, 256, lds, stream>>>(in, zbuf, w, bias, hbuf, cbuf, t, tc, TcMax, B, T, Cin, hid, H, W, nOcg, BPP); break;
            case 2: step_h<1, 1, false><<<blocks, 256, lds, stream>>>(in, zbuf, w, bias, hbuf, cbuf, t, tc, TcMax, B, T, Cin, hid, H, W, nOcg, BPP); break;
            case 3: step_h<4, 1, false><<<blocks, 256, lds, stream>>>(in, zbuf, w, bias, hbuf, cbuf, t, tc, TcMax, B, T, Cin, hid, H, W, nOcg, BPP); break;
        }
    }
}

extern "C" void kernel_launch(void* const* d_in, const int* in_sizes, int n_in,
                              void* d_out, int out_size, void* d_ws, size_t ws_size,
                              hipStream_t stream)
{
    const int B = 8, T = 40;
    const float* x = (const float*)d_in[0];

    // workspace layout (floats)
    float* hbuf  = (float*)d_ws;                 // 20,971,520
    float* pbuf  = hbuf + (size_t)20971520;      //  5,242,880
    float* cbuf  = pbuf + (size_t)5242880;       //    524,288
    float* stats = cbuf + (size_t)524288;        //        128
    float* zbuf  = stats + 128;                  //  8,388,608 (zx chunks)
    const size_t needF = 20971520ULL + 5242880 + 524288 + 128 + 8388608;
    const bool use_zx = ws_size >= needF * sizeof(float);

    struct LCfg { int Cin, hid, H, W, Tc; };
    const LCfg L[4] = { {1, 16, 64, 64, 4}, {16, 32, 32, 32, 8},
                        {32, 64, 16, 16, 16}, {64, 64, 8, 8, 40} };

    const float* in = x;
    for (int l = 0; l < 4; ++l) {
        const float* w     = (const float*)d_in[1 + 4 * l];
        const float* bias  = (const float*)d_in[2 + 4 * l];
        const float* gamma = (const float*)d_in[3 + 4 * l];
        const float* beta  = (const float*)d_in[4 + 4 * l];
        const int Cin = L[l].Cin, hid = L[l].hid, H = L[l].H, W = L[l].W;
        const int HW = H * W, Ctot = Cin + hid;
        const int TcMax = L[l].Tc;

        if (use_zx) {
            for (int t0 = 0; t0 < T; t0 += TcMax) {
                int TcAct = (T - t0 < TcMax) ? (T - t0) : TcMax;
                int tot = B * TcAct * hid * HW;
                zx_conv<<<(tot + 255) / 256, 256, 0, stream>>>(
                    in, w, bias, zbuf, t0, TcAct, TcMax, B, T, Cin, Ctot, hid, H, W);
                for (int t = t0; t < t0 + TcAct; ++t)
                    launch_step(l, true, in, zbuf, w, bias, hbuf, cbuf,
                                t, t - t0, TcMax, B, T, Cin, hid, H, W, stream);
            }
        } else {
            for (int t = 0; t < T; ++t)
                launch_step(l, false, in, zbuf, w, bias, hbuf, cbuf,
                            t, 0, 1, B, T, Cin, hid, H, W, stream);
        }

        hipMemsetAsync(stats, 0, 2 * hid * sizeof(float), stream);
        bn_stats<<<dim3(hid, 80), 256, 0, stream>>>(hbuf, stats, B * T, hid, HW);

        int ptotal = B * T * hid * (H / 2) * (W / 2);
        float invN = 1.0f / ((float)(B * T) * (float)HW);
        bn_relu_pool<<<(ptotal + 255) / 256, 256, 0, stream>>>(
            hbuf, stats, gamma, beta, pbuf, B * T, hid, H, W, invN);
        in = pbuf;
    }

    const float* fc1w = (const float*)d_in[17];
    const float* fc1b = (const float*)d_in[18];
    const float* fc2w = (const float*)d_in[19];
    const float* fc2b = (const float*)d_in[20];
    fc_head<<<B * T, 128, 0, stream>>>(pbuf, fc1w, fc1b, fc2w, fc2b, (float*)d_out);
}